// Round 12
// baseline (258.554 us; speedup 1.0000x reference)
//
#include <hip/hip_runtime.h>

// C3-style layer via MFMA implicit GEMM, R11 = R10 + paired-d-step sliding
// window: chains (d, d+2) share B-slots -> per kx, 4 ds_read_b128 feed 6
// MFMAs across 2 independent accumulators (ILP-2, 1/3 fewer LDS reads).
// x[32,6,512,512] f32 -> out[32,16,508,508] f32 (5x5 VALID conv; sparse
// oc<-ic connectivity via zero weights in dense [16,6,5,5] kernel).
//
// GEMM per kx: K=(window_row, icp8), M=32=(2 output rows x 16 oc), N=32 px.
// A-frags d-independent (prep kernel, verified R6).  Block = 64 px x 16 rows;
// 4 waves = 2 px-strips x 2 d-halves (verified R8/R10 assignment).

#define OW 508
#define BX 64     // output px per block; 2 strips x 32
#define BY 16     // output rows per block
#define TC 68     // staged columns = BX + 4
#define TR 21     // uint4 slots per column (20 rows; odd pitch spreads banks)

typedef _Float16 h8 __attribute__((ext_vector_type(8)));
typedef _Float16 h2 __attribute__((ext_vector_type(2)));
typedef float f32x16 __attribute__((ext_vector_type(16)));

__device__ __constant__ int d_CH3[6][3] = {
    {0,1,2},{1,2,3},{2,3,4},{3,4,5},{0,4,5},{0,1,5}};
__device__ __constant__ int d_CH4[9][4] = {
    {0,1,2,3},{1,2,3,4},{2,3,4,5},{0,3,4,5},{0,1,4,5},
    {0,1,2,5},{0,1,3,4},{1,2,4,5},{0,2,3,5}};

// ws: bias f32[16] | AF ushort[15*64*8]
// AF[((kx*3+ch)*64 + lane)*8 + e]: A-frag: oc=lane&15, dy=(lane>>4)&1,
// rr=lane>>5, ky=ch*2+rr-dy; value W[oc][e][ky][kx] or 0.  (verified R6)
__global__ void prep_weights(const float* __restrict__ w3, const float* __restrict__ b3,
                             const float* __restrict__ w4, const float* __restrict__ b4,
                             const float* __restrict__ w6, const float* __restrict__ b6,
                             float* __restrict__ bias, unsigned short* __restrict__ AF) {
    __shared__ float Wfull[16 * 6 * 25];   // dense [oc][ic][tap]
    const int tid = threadIdx.x;
    for (int i = tid; i < 16 * 6 * 25; i += 256) Wfull[i] = 0.f;
    __syncthreads();
    for (int i = tid; i < 6 * 3 * 25; i += 256) {
        int oc = i / 75, r = i % 75, c = r / 25, t = r % 25;
        Wfull[(oc * 6 + d_CH3[oc][c]) * 25 + t] = w3[i];
    }
    for (int i = tid; i < 9 * 4 * 25; i += 256) {
        int o = i / 100, r = i % 100, c = r / 25, t = r % 25;
        Wfull[((6 + o) * 6 + d_CH4[o][c]) * 25 + t] = w4[i];
    }
    for (int i = tid; i < 6 * 25; i += 256) Wfull[15 * 150 + i] = w6[i];
    __syncthreads();
    for (int i = tid; i < 15 * 64 * 8; i += 256) {
        int e = i & 7, lane = (i >> 3) & 63, q = i >> 9;   // q = kx*3+ch
        int kx = q / 3, ch = q % 3;
        int oc = lane & 15, dy = (lane >> 4) & 1, rr = lane >> 5;
        int ky = ch * 2 + rr - dy;
        float w = 0.f;
        if (e < 6 && ky >= 0 && ky <= 4) w = Wfull[(oc * 6 + e) * 25 + ky * 5 + kx];
        _Float16 hw = (_Float16)w;
        AF[i] = __builtin_bit_cast(unsigned short, hw);
    }
    if (tid < 6)        bias[tid] = b3[tid];
    else if (tid < 15)  bias[tid] = b4[tid - 6];
    else if (tid == 15) bias[tid] = b6[0];
}

__global__ __launch_bounds__(256, 4) void conv_mfma(
        const float* __restrict__ x, const unsigned short* __restrict__ AF,
        const float* __restrict__ bias, float* __restrict__ out) {
    __shared__ uint4 T4[TC * TR];   // 22848 B -> 6-7 blocks/CU

    const int tid = threadIdx.x;
    const int gx0 = blockIdx.x * BX;
    const int oy0 = blockIdx.y * BY;
    const int bz  = blockIdx.z;
    const float* xb = x + (size_t)bz * 6 * 512 * 512;
    unsigned int* Tw = (unsigned int*)T4;

    const int lane = tid & 63;
    const int h = lane >> 5;            // K-half / oc-half (verified R6 mapping)

    // global loads issued before the barrier -> overlap with LDS staging
    h8 afr[15];
    #pragma unroll
    for (int q = 0; q < 15; ++q)
        afr[q] = *reinterpret_cast<const h8*>(AF + (q * 64 + lane) * 8);

    f32x16 binit;
    #pragma unroll
    for (int reg = 0; reg < 16; ++reg)
        binit[reg] = bias[((reg & 3) + 8 * ((reg >> 2) & 1) + 4 * h) & 15];

    // -- zero the never-staged ip=3 words (icp 6,7); disjoint from stage writes
    for (int i = tid; i < TC * TR; i += 256) Tw[i * 4 + 3] = 0u;

    // -- stage rows 0..19, ic-pairs 0..2, col-pairs 0..33 (zero outside image)
    for (int idx = tid; idx < 34 * 3 * 20; idx += 256) {
        int cp = idx % 34;
        int ip = (idx / 34) % 3;
        int rr = idx / 102;
        int gy = oy0 + rr;
        int c = 2 * cp, gx = gx0 + c;
        float2 a = {0.f, 0.f}, b = {0.f, 0.f};
        if (gy < 512 && gx < 512) {     // gx even -> gx<=510, float2 in-row safe
            a = *(const float2*)(xb + ((size_t)(2 * ip) * 512 + gy) * 512 + gx);
            b = *(const float2*)(xb + ((size_t)(2 * ip + 1) * 512 + gy) * 512 + gx);
        }
        h2 w0; w0.x = (_Float16)a.x; w0.y = (_Float16)b.x;
        h2 w1; w1.x = (_Float16)a.y; w1.y = (_Float16)b.y;
        int q0 = c * TR + rr;
        Tw[q0 * 4 + ip]        = __builtin_bit_cast(unsigned int, w0);
        Tw[(q0 + TR) * 4 + ip] = __builtin_bit_cast(unsigned int, w1);
    }
    __syncthreads();                    // the ONLY barrier

    const int wv = tid >> 6;
    const int s  = wv & 1;              // px strip
    const int dh = wv >> 1;             // d half
    const int colb = s * 32 + (lane & 31);
    const int px = gx0 + colb;
    const bool pxok = (px < OW);
    const size_t cs = (size_t)OW * OW;
    float* ob = out + ((size_t)bz * 16 + 4 * h) * cs + px;

    #pragma unroll 1
    for (int dd = 0; dd < 8; dd += 4) {
        const int d0 = dh * 8 + dd;     // chain A rows (d0, d0+1); B (d0+2, d0+3)
        f32x16 accA = binit;
        f32x16 accB = binit;
        #pragma unroll
        for (int kx = 0; kx < 5; ++kx) {
            const uint4* cb = &T4[(colb + kx) * TR + d0 + h];
            h8 b0 = *reinterpret_cast<const h8*>(&cb[0]);
            h8 b1 = *reinterpret_cast<const h8*>(&cb[2]);
            h8 b2 = *reinterpret_cast<const h8*>(&cb[4]);
            h8 b3 = *reinterpret_cast<const h8*>(&cb[6]);
            accA = __builtin_amdgcn_mfma_f32_32x32x16_f16(afr[kx * 3 + 0], b0, accA, 0, 0, 0);
            accB = __builtin_amdgcn_mfma_f32_32x32x16_f16(afr[kx * 3 + 0], b1, accB, 0, 0, 0);
            accA = __builtin_amdgcn_mfma_f32_32x32x16_f16(afr[kx * 3 + 1], b1, accA, 0, 0, 0);
            accB = __builtin_amdgcn_mfma_f32_32x32x16_f16(afr[kx * 3 + 1], b2, accB, 0, 0, 0);
            accA = __builtin_amdgcn_mfma_f32_32x32x16_f16(afr[kx * 3 + 2], b2, accA, 0, 0, 0);
            accB = __builtin_amdgcn_mfma_f32_32x32x16_f16(afr[kx * 3 + 2], b3, accB, 0, 0, 0);
        }
        #pragma unroll
        for (int dy = 0; dy < 2; ++dy) {
            #pragma unroll
            for (int r8 = 0; r8 < 8; ++r8) {
                const int reg = dy * 8 + r8;
                const int ocb = (r8 & 3) + 8 * (r8 >> 2);
                const int oyA = oy0 + d0 + dy;
                const int oyB = oyA + 2;
                if (oyA < OW && pxok)
                    ob[(size_t)ocb * cs + (size_t)oyA * OW] = accA[reg];
                if (oyB < OW && pxok)
                    ob[(size_t)ocb * cs + (size_t)oyB * OW] = accB[reg];
            }
        }
    }
}

extern "C" void kernel_launch(void* const* d_in, const int* in_sizes, int n_in,
                              void* d_out, int out_size, void* d_ws, size_t ws_size,
                              hipStream_t stream) {
    const float* x  = (const float*)d_in[0];
    const float* w3 = (const float*)d_in[1];
    const float* b3 = (const float*)d_in[2];
    const float* w4 = (const float*)d_in[3];
    const float* b4 = (const float*)d_in[4];
    const float* w6 = (const float*)d_in[5];
    const float* b6 = (const float*)d_in[6];
    float* out = (float*)d_out;

    float* bias        = (float*)d_ws;                    // 16 f32
    unsigned short* AF = (unsigned short*)(bias + 16);    // 7680 u16

    prep_weights<<<1, 256, 0, stream>>>(w3, b3, w4, b4, w6, b6, bias, AF);

    dim3 grid((OW + BX - 1) / BX, (OW + BY - 1) / BY, 32);  // 8, 32, 32
    conv_mfma<<<grid, 256, 0, stream>>>(x, AF, bias, out);
}

// Round 13
// 255.916 us; speedup vs baseline: 1.0103x; 1.0103x over previous
//
#include <hip/hip_runtime.h>

// C3-style layer via MFMA implicit GEMM, R12 = R11 with a slot-major LDS
// layout (block = slot*68 + col): wave B-reads are 32 CONTIGUOUS 16B blocks
// (zero bank conflicts); staging packs 6 channels into one ds_write_b128 per
// column (1360 writes vs 4080 b32).  Compute/A-frag/C mappings verbatim from
// verified R6/R10/R11.
// x[32,6,512,512] f32 -> out[32,16,508,508] f32 (5x5 VALID conv; sparse
// oc<-ic connectivity via zero weights in dense [16,6,5,5] kernel).

#define OW 508
#define BX 64     // output px per block; 2 strips x 32
#define BY 16     // output rows per block
#define TC 68     // staged columns = BX + 4
#define NS 20     // window-row slots

typedef _Float16 h8 __attribute__((ext_vector_type(8)));
typedef _Float16 h2 __attribute__((ext_vector_type(2)));
typedef float f32x16 __attribute__((ext_vector_type(16)));

__device__ __constant__ int d_CH3[6][3] = {
    {0,1,2},{1,2,3},{2,3,4},{3,4,5},{0,4,5},{0,1,5}};
__device__ __constant__ int d_CH4[9][4] = {
    {0,1,2,3},{1,2,3,4},{2,3,4,5},{0,3,4,5},{0,1,4,5},
    {0,1,2,5},{0,1,3,4},{1,2,4,5},{0,2,3,5}};

// ws: bias f32[16] | AF ushort[15*64*8]
// AF[((kx*3+ch)*64 + lane)*8 + e]: A-frag: oc=lane&15, dy=(lane>>4)&1,
// rr=lane>>5, ky=ch*2+rr-dy; value W[oc][e][ky][kx] or 0.  (verified R6)
__global__ void prep_weights(const float* __restrict__ w3, const float* __restrict__ b3,
                             const float* __restrict__ w4, const float* __restrict__ b4,
                             const float* __restrict__ w6, const float* __restrict__ b6,
                             float* __restrict__ bias, unsigned short* __restrict__ AF) {
    __shared__ float Wfull[16 * 6 * 25];   // dense [oc][ic][tap]
    const int tid = threadIdx.x;
    for (int i = tid; i < 16 * 6 * 25; i += 256) Wfull[i] = 0.f;
    __syncthreads();
    for (int i = tid; i < 6 * 3 * 25; i += 256) {
        int oc = i / 75, r = i % 75, c = r / 25, t = r % 25;
        Wfull[(oc * 6 + d_CH3[oc][c]) * 25 + t] = w3[i];
    }
    for (int i = tid; i < 9 * 4 * 25; i += 256) {
        int o = i / 100, r = i % 100, c = r / 25, t = r % 25;
        Wfull[((6 + o) * 6 + d_CH4[o][c]) * 25 + t] = w4[i];
    }
    for (int i = tid; i < 6 * 25; i += 256) Wfull[15 * 150 + i] = w6[i];
    __syncthreads();
    for (int i = tid; i < 15 * 64 * 8; i += 256) {
        int e = i & 7, lane = (i >> 3) & 63, q = i >> 9;   // q = kx*3+ch
        int kx = q / 3, ch = q % 3;
        int oc = lane & 15, dy = (lane >> 4) & 1, rr = lane >> 5;
        int ky = ch * 2 + rr - dy;
        float w = 0.f;
        if (e < 6 && ky >= 0 && ky <= 4) w = Wfull[(oc * 6 + e) * 25 + ky * 5 + kx];
        _Float16 hw = (_Float16)w;
        AF[i] = __builtin_bit_cast(unsigned short, hw);
    }
    if (tid < 6)        bias[tid] = b3[tid];
    else if (tid < 15)  bias[tid] = b4[tid - 6];
    else if (tid == 15) bias[tid] = b6[0];
}

__global__ __launch_bounds__(256, 4) void conv_mfma(
        const float* __restrict__ x, const unsigned short* __restrict__ AF,
        const float* __restrict__ bias, float* __restrict__ out) {
    __shared__ uint4 T4[NS * TC];   // 21760 B, slot-major: block = slot*TC + col

    const int tid = threadIdx.x;
    const int gx0 = blockIdx.x * BX;
    const int oy0 = blockIdx.y * BY;
    const int bz  = blockIdx.z;
    const float* xb = x + (size_t)bz * 6 * 512 * 512;

    const int lane = tid & 63;
    const int h = lane >> 5;            // K-half / oc-half (verified R6 mapping)

    // global loads issued before staging -> overlap
    h8 afr[15];
    #pragma unroll
    for (int q = 0; q < 15; ++q)
        afr[q] = *reinterpret_cast<const h8*>(AF + (q * 64 + lane) * 8);

    f32x16 binit;
    #pragma unroll
    for (int reg = 0; reg < 16; ++reg)
        binit[reg] = bias[((reg & 3) + 8 * ((reg >> 2) & 1) + 4 * h) & 15];

    // -- stage: item = (col-pair cp, row rr); 6 float2 plane loads -> two
    //    packed uint4 (ic pairs in words 0..2, word 3 = zero) -> 2 ds_write_b128
    #pragma unroll
    for (int k = 0; k < 3; ++k) {
        int idx = tid + k * 256;
        if (idx < 34 * NS) {
            int cp = idx % 34;
            int rr = idx / 34;
            int c = 2 * cp, gx = gx0 + c, gy = oy0 + rr;
            float2 v[6];
            #pragma unroll
            for (int ic = 0; ic < 6; ++ic) v[ic] = (float2){0.f, 0.f};
            if (gy < 512 && gx < 512) {
                const float* rp = xb + (size_t)gy * 512 + gx;
                #pragma unroll
                for (int ic = 0; ic < 6; ++ic)
                    v[ic] = *(const float2*)(rp + (size_t)ic * 262144);
            }
            h2 a0; a0.x = (_Float16)v[0].x; a0.y = (_Float16)v[1].x;
            h2 a1; a1.x = (_Float16)v[2].x; a1.y = (_Float16)v[3].x;
            h2 a2; a2.x = (_Float16)v[4].x; a2.y = (_Float16)v[5].x;
            h2 b0; b0.x = (_Float16)v[0].y; b0.y = (_Float16)v[1].y;
            h2 b1; b1.x = (_Float16)v[2].y; b1.y = (_Float16)v[3].y;
            h2 b2; b2.x = (_Float16)v[4].y; b2.y = (_Float16)v[5].y;
            uint4 wA, wB;
            wA.x = __builtin_bit_cast(unsigned int, a0);
            wA.y = __builtin_bit_cast(unsigned int, a1);
            wA.z = __builtin_bit_cast(unsigned int, a2);
            wA.w = 0u;
            wB.x = __builtin_bit_cast(unsigned int, b0);
            wB.y = __builtin_bit_cast(unsigned int, b1);
            wB.z = __builtin_bit_cast(unsigned int, b2);
            wB.w = 0u;
            T4[rr * TC + c]     = wA;
            T4[rr * TC + c + 1] = wB;
        }
    }
    __syncthreads();                    // the ONLY barrier

    const int wv = tid >> 6;
    const int s  = wv & 1;              // px strip
    const int dh = wv >> 1;             // d half
    const int colb = s * 32 + (lane & 31);
    const int px = gx0 + colb;
    const bool pxok = (px < OW);
    const size_t cs = (size_t)OW * OW;
    float* ob = out + ((size_t)bz * 16 + 4 * h) * cs + px;

    #pragma unroll 1
    for (int dd = 0; dd < 8; dd += 4) {
        const int d0 = dh * 8 + dd;     // chain A rows (d0, d0+1); B (d0+2, d0+3)
        f32x16 accA = binit;
        f32x16 accB = binit;
        #pragma unroll
        for (int kx = 0; kx < 5; ++kx) {
            const uint4* cb = &T4[(d0 + h) * TC + colb + kx];
            h8 b0 = *reinterpret_cast<const h8*>(&cb[0]);        // slot d0+h
            h8 b1 = *reinterpret_cast<const h8*>(&cb[2 * TC]);   // +2
            h8 b2 = *reinterpret_cast<const h8*>(&cb[4 * TC]);   // +4
            h8 b3 = *reinterpret_cast<const h8*>(&cb[6 * TC]);   // +6 (<=19)
            accA = __builtin_amdgcn_mfma_f32_32x32x16_f16(afr[kx * 3 + 0], b0, accA, 0, 0, 0);
            accB = __builtin_amdgcn_mfma_f32_32x32x16_f16(afr[kx * 3 + 0], b1, accB, 0, 0, 0);
            accA = __builtin_amdgcn_mfma_f32_32x32x16_f16(afr[kx * 3 + 1], b1, accA, 0, 0, 0);
            accB = __builtin_amdgcn_mfma_f32_32x32x16_f16(afr[kx * 3 + 1], b2, accB, 0, 0, 0);
            accA = __builtin_amdgcn_mfma_f32_32x32x16_f16(afr[kx * 3 + 2], b2, accA, 0, 0, 0);
            accB = __builtin_amdgcn_mfma_f32_32x32x16_f16(afr[kx * 3 + 2], b3, accB, 0, 0, 0);
        }
        #pragma unroll
        for (int dy = 0; dy < 2; ++dy) {
            #pragma unroll
            for (int r8 = 0; r8 < 8; ++r8) {
                const int reg = dy * 8 + r8;
                const int ocb = (r8 & 3) + 8 * (r8 >> 2);
                const int oyA = oy0 + d0 + dy;
                const int oyB = oyA + 2;
                if (oyA < OW && pxok)
                    ob[(size_t)ocb * cs + (size_t)oyA * OW] = accA[reg];
                if (oyB < OW && pxok)
                    ob[(size_t)ocb * cs + (size_t)oyB * OW] = accB[reg];
            }
        }
    }
}

extern "C" void kernel_launch(void* const* d_in, const int* in_sizes, int n_in,
                              void* d_out, int out_size, void* d_ws, size_t ws_size,
                              hipStream_t stream) {
    const float* x  = (const float*)d_in[0];
    const float* w3 = (const float*)d_in[1];
    const float* b3 = (const float*)d_in[2];
    const float* w4 = (const float*)d_in[3];
    const float* b4 = (const float*)d_in[4];
    const float* w6 = (const float*)d_in[5];
    const float* b6 = (const float*)d_in[6];
    float* out = (float*)d_out;

    float* bias        = (float*)d_ws;                    // 16 f32
    unsigned short* AF = (unsigned short*)(bias + 16);    // 7680 u16

    prep_weights<<<1, 256, 0, stream>>>(w3, b3, w4, b4, w6, b6, bias, AF);

    dim3 grid((OW + BX - 1) / BX, (OW + BY - 1) / BY, 32);  // 8, 32, 32
    conv_mfma<<<grid, 256, 0, stream>>>(x, AF, bias, out);
}

// Round 14
// 242.435 us; speedup vs baseline: 1.0665x; 1.0556x over previous
//
#include <hip/hip_runtime.h>

// C3-style layer via MFMA implicit GEMM, R13 = R12 + XCD-coherent block remap:
// XCD = linear_id & 7 (round-robin dispatch), so default mapping puts the
// x-strip boundary (shared halo columns + SPLIT OUTPUT CACHE LINES: row pitch
// 2032B !≡ 0 mod 128) across non-coherent per-XCD L2s -> partial-line HBM
// writes + halo refetch.  Remap gives each XCD 4 whole batches; all sharing
// becomes XCD-local.  Compute/layout verbatim from verified R12.
// x[32,6,512,512] f32 -> out[32,16,508,508] f32 (5x5 VALID conv; sparse
// oc<-ic connectivity via zero weights in dense [16,6,5,5] kernel).

#define OW 508
#define BX 64     // output px per block; 2 strips x 32
#define BY 16     // output rows per block
#define TC 68     // staged columns = BX + 4
#define NS 20     // window-row slots

typedef _Float16 h8 __attribute__((ext_vector_type(8)));
typedef _Float16 h2 __attribute__((ext_vector_type(2)));
typedef float f32x16 __attribute__((ext_vector_type(16)));

__device__ __constant__ int d_CH3[6][3] = {
    {0,1,2},{1,2,3},{2,3,4},{3,4,5},{0,4,5},{0,1,5}};
__device__ __constant__ int d_CH4[9][4] = {
    {0,1,2,3},{1,2,3,4},{2,3,4,5},{0,3,4,5},{0,1,4,5},
    {0,1,2,5},{0,1,3,4},{1,2,4,5},{0,2,3,5}};

// ws: bias f32[16] | AF ushort[15*64*8]
// AF[((kx*3+ch)*64 + lane)*8 + e]: A-frag: oc=lane&15, dy=(lane>>4)&1,
// rr=lane>>5, ky=ch*2+rr-dy; value W[oc][e][ky][kx] or 0.  (verified R6)
__global__ void prep_weights(const float* __restrict__ w3, const float* __restrict__ b3,
                             const float* __restrict__ w4, const float* __restrict__ b4,
                             const float* __restrict__ w6, const float* __restrict__ b6,
                             float* __restrict__ bias, unsigned short* __restrict__ AF) {
    __shared__ float Wfull[16 * 6 * 25];   // dense [oc][ic][tap]
    const int tid = threadIdx.x;
    for (int i = tid; i < 16 * 6 * 25; i += 256) Wfull[i] = 0.f;
    __syncthreads();
    for (int i = tid; i < 6 * 3 * 25; i += 256) {
        int oc = i / 75, r = i % 75, c = r / 25, t = r % 25;
        Wfull[(oc * 6 + d_CH3[oc][c]) * 25 + t] = w3[i];
    }
    for (int i = tid; i < 9 * 4 * 25; i += 256) {
        int o = i / 100, r = i % 100, c = r / 25, t = r % 25;
        Wfull[((6 + o) * 6 + d_CH4[o][c]) * 25 + t] = w4[i];
    }
    for (int i = tid; i < 6 * 25; i += 256) Wfull[15 * 150 + i] = w6[i];
    __syncthreads();
    for (int i = tid; i < 15 * 64 * 8; i += 256) {
        int e = i & 7, lane = (i >> 3) & 63, q = i >> 9;   // q = kx*3+ch
        int kx = q / 3, ch = q % 3;
        int oc = lane & 15, dy = (lane >> 4) & 1, rr = lane >> 5;
        int ky = ch * 2 + rr - dy;
        float w = 0.f;
        if (e < 6 && ky >= 0 && ky <= 4) w = Wfull[(oc * 6 + e) * 25 + ky * 5 + kx];
        _Float16 hw = (_Float16)w;
        AF[i] = __builtin_bit_cast(unsigned short, hw);
    }
    if (tid < 6)        bias[tid] = b3[tid];
    else if (tid < 15)  bias[tid] = b4[tid - 6];
    else if (tid == 15) bias[tid] = b6[0];
}

__global__ __launch_bounds__(256, 4) void conv_mfma(
        const float* __restrict__ x, const unsigned short* __restrict__ AF,
        const float* __restrict__ bias, float* __restrict__ out) {
    __shared__ uint4 T4[NS * TC];   // 21760 B, slot-major: block = slot*TC + col

    const int tid = threadIdx.x;

    // ---- XCD-coherent remap (bijective on 8192 blocks).  Dispatch order id
    // round-robins XCDs -> xcd = id&7.  Give each XCD 4 whole batches; within
    // a slab sweep bx fastest (x-neighbors temporally adjacent, same L2).
    const int id  = blockIdx.x + 8 * (blockIdx.y + 32 * blockIdx.z);
    const int xcd = id & 7;
    const int pos = id >> 3;            // 0..1023
    const int bz  = xcd * 4 + (pos >> 8);
    const int r_  = pos & 255;
    const int by  = r_ >> 3;
    const int bx  = r_ & 7;

    const int gx0 = bx * BX;
    const int oy0 = by * BY;
    const float* xb = x + (size_t)bz * 6 * 512 * 512;

    const int lane = tid & 63;
    const int h = lane >> 5;            // K-half / oc-half (verified R6 mapping)

    // global loads issued before staging -> overlap
    h8 afr[15];
    #pragma unroll
    for (int q = 0; q < 15; ++q)
        afr[q] = *reinterpret_cast<const h8*>(AF + (q * 64 + lane) * 8);

    f32x16 binit;
    #pragma unroll
    for (int reg = 0; reg < 16; ++reg)
        binit[reg] = bias[((reg & 3) + 8 * ((reg >> 2) & 1) + 4 * h) & 15];

    // -- stage: item = (col-pair cp, row rr); 6 float2 plane loads -> two
    //    packed uint4 (ic pairs in words 0..2, word 3 = zero) -> 2 ds_write_b128
    #pragma unroll
    for (int k = 0; k < 3; ++k) {
        int idx = tid + k * 256;
        if (idx < 34 * NS) {
            int cp = idx % 34;
            int rr = idx / 34;
            int c = 2 * cp, gx = gx0 + c, gy = oy0 + rr;
            float2 v[6];
            #pragma unroll
            for (int ic = 0; ic < 6; ++ic) v[ic] = (float2){0.f, 0.f};
            if (gy < 512 && gx < 512) {
                const float* rp = xb + (size_t)gy * 512 + gx;
                #pragma unroll
                for (int ic = 0; ic < 6; ++ic)
                    v[ic] = *(const float2*)(rp + (size_t)ic * 262144);
            }
            h2 a0; a0.x = (_Float16)v[0].x; a0.y = (_Float16)v[1].x;
            h2 a1; a1.x = (_Float16)v[2].x; a1.y = (_Float16)v[3].x;
            h2 a2; a2.x = (_Float16)v[4].x; a2.y = (_Float16)v[5].x;
            h2 b0; b0.x = (_Float16)v[0].y; b0.y = (_Float16)v[1].y;
            h2 b1; b1.x = (_Float16)v[2].y; b1.y = (_Float16)v[3].y;
            h2 b2; b2.x = (_Float16)v[4].y; b2.y = (_Float16)v[5].y;
            uint4 wA, wB;
            wA.x = __builtin_bit_cast(unsigned int, a0);
            wA.y = __builtin_bit_cast(unsigned int, a1);
            wA.z = __builtin_bit_cast(unsigned int, a2);
            wA.w = 0u;
            wB.x = __builtin_bit_cast(unsigned int, b0);
            wB.y = __builtin_bit_cast(unsigned int, b1);
            wB.z = __builtin_bit_cast(unsigned int, b2);
            wB.w = 0u;
            T4[rr * TC + c]     = wA;
            T4[rr * TC + c + 1] = wB;
        }
    }
    __syncthreads();                    // the ONLY barrier

    const int wv = tid >> 6;
    const int s  = wv & 1;              // px strip
    const int dh = wv >> 1;             // d half
    const int colb = s * 32 + (lane & 31);
    const int px = gx0 + colb;
    const bool pxok = (px < OW);
    const size_t cs = (size_t)OW * OW;
    float* ob = out + ((size_t)bz * 16 + 4 * h) * cs + px;

    #pragma unroll 1
    for (int dd = 0; dd < 8; dd += 4) {
        const int d0 = dh * 8 + dd;     // chain A rows (d0, d0+1); B (d0+2, d0+3)
        f32x16 accA = binit;
        f32x16 accB = binit;
        #pragma unroll
        for (int kx = 0; kx < 5; ++kx) {
            const uint4* cb = &T4[(d0 + h) * TC + colb + kx];
            h8 b0 = *reinterpret_cast<const h8*>(&cb[0]);        // slot d0+h
            h8 b1 = *reinterpret_cast<const h8*>(&cb[2 * TC]);   // +2
            h8 b2 = *reinterpret_cast<const h8*>(&cb[4 * TC]);   // +4
            h8 b3 = *reinterpret_cast<const h8*>(&cb[6 * TC]);   // +6 (<=19)
            accA = __builtin_amdgcn_mfma_f32_32x32x16_f16(afr[kx * 3 + 0], b0, accA, 0, 0, 0);
            accB = __builtin_amdgcn_mfma_f32_32x32x16_f16(afr[kx * 3 + 0], b1, accB, 0, 0, 0);
            accA = __builtin_amdgcn_mfma_f32_32x32x16_f16(afr[kx * 3 + 1], b1, accA, 0, 0, 0);
            accB = __builtin_amdgcn_mfma_f32_32x32x16_f16(afr[kx * 3 + 1], b2, accB, 0, 0, 0);
            accA = __builtin_amdgcn_mfma_f32_32x32x16_f16(afr[kx * 3 + 2], b2, accA, 0, 0, 0);
            accB = __builtin_amdgcn_mfma_f32_32x32x16_f16(afr[kx * 3 + 2], b3, accB, 0, 0, 0);
        }
        #pragma unroll
        for (int dy = 0; dy < 2; ++dy) {
            #pragma unroll
            for (int r8 = 0; r8 < 8; ++r8) {
                const int reg = dy * 8 + r8;
                const int ocb = (r8 & 3) + 8 * (r8 >> 2);
                const int oyA = oy0 + d0 + dy;
                const int oyB = oyA + 2;
                if (oyA < OW && pxok)
                    ob[(size_t)ocb * cs + (size_t)oyA * OW] = accA[reg];
                if (oyB < OW && pxok)
                    ob[(size_t)ocb * cs + (size_t)oyB * OW] = accB[reg];
            }
        }
    }
}

extern "C" void kernel_launch(void* const* d_in, const int* in_sizes, int n_in,
                              void* d_out, int out_size, void* d_ws, size_t ws_size,
                              hipStream_t stream) {
    const float* x  = (const float*)d_in[0];
    const float* w3 = (const float*)d_in[1];
    const float* b3 = (const float*)d_in[2];
    const float* w4 = (const float*)d_in[3];
    const float* b4 = (const float*)d_in[4];
    const float* w6 = (const float*)d_in[5];
    const float* b6 = (const float*)d_in[6];
    float* out = (float*)d_out;

    float* bias        = (float*)d_ws;                    // 16 f32
    unsigned short* AF = (unsigned short*)(bias + 16);    // 7680 u16

    prep_weights<<<1, 256, 0, stream>>>(w3, b3, w4, b4, w6, b6, bias, AF);

    dim3 grid(8, 32, 32);   // remapped in-kernel to XCD-coherent slabs
    conv_mfma<<<grid, 256, 0, stream>>>(x, AF, bias, out);
}

// Round 15
// 227.044 us; speedup vs baseline: 1.1388x; 1.0678x over previous
//
#include <hip/hip_runtime.h>

// C3-style layer via MFMA implicit GEMM, R14: ring-buffered y-walk on the
// verified slot-major tile.  Block = 64px x 32 output rows, 512 threads
// (8 waves = 2 px-strips x 2 d-halves x 2 chains).  32-slot LDS row ring
// (slot = gy&31); each phase computes 8 rows while the NEXT+2 phase's rows
// are in flight from HBM in registers (issue-early / commit-late, T14).
// Keeps R13's XCD-coherent batch-slab remap.  All MFMA/A-frag/C mappings
// verbatim from verified R6..R13.
// x[32,6,512,512] f32 -> out[32,16,508,508] f32 (5x5 VALID conv; sparse
// oc<-ic connectivity via zero weights in dense [16,6,5,5] kernel).

#define OW 508
#define BX 64     // output px per block; 2 strips x 32
#define TC 68     // staged columns = BX + 4
#define RM 31     // ring mask (32 slots)

typedef _Float16 h8 __attribute__((ext_vector_type(8)));
typedef _Float16 h2 __attribute__((ext_vector_type(2)));
typedef float f32x16 __attribute__((ext_vector_type(16)));

__device__ __constant__ int d_CH3[6][3] = {
    {0,1,2},{1,2,3},{2,3,4},{3,4,5},{0,4,5},{0,1,5}};
__device__ __constant__ int d_CH4[9][4] = {
    {0,1,2,3},{1,2,3,4},{2,3,4,5},{0,3,4,5},{0,1,4,5},
    {0,1,2,5},{0,1,3,4},{1,2,4,5},{0,2,3,5}};

// ws: bias f32[16] | AF ushort[15*64*8]
// AF[((kx*3+ch)*64 + lane)*8 + e]: A-frag: oc=lane&15, dy=(lane>>4)&1,
// rr=lane>>5, ky=ch*2+rr-dy; value W[oc][e][ky][kx] or 0.  (verified R6)
__global__ void prep_weights(const float* __restrict__ w3, const float* __restrict__ b3,
                             const float* __restrict__ w4, const float* __restrict__ b4,
                             const float* __restrict__ w6, const float* __restrict__ b6,
                             float* __restrict__ bias, unsigned short* __restrict__ AF) {
    __shared__ float Wfull[16 * 6 * 25];   // dense [oc][ic][tap]
    const int tid = threadIdx.x;
    for (int i = tid; i < 16 * 6 * 25; i += 256) Wfull[i] = 0.f;
    __syncthreads();
    for (int i = tid; i < 6 * 3 * 25; i += 256) {
        int oc = i / 75, r = i % 75, c = r / 25, t = r % 25;
        Wfull[(oc * 6 + d_CH3[oc][c]) * 25 + t] = w3[i];
    }
    for (int i = tid; i < 9 * 4 * 25; i += 256) {
        int o = i / 100, r = i % 100, c = r / 25, t = r % 25;
        Wfull[((6 + o) * 6 + d_CH4[o][c]) * 25 + t] = w4[i];
    }
    for (int i = tid; i < 6 * 25; i += 256) Wfull[15 * 150 + i] = w6[i];
    __syncthreads();
    for (int i = tid; i < 15 * 64 * 8; i += 256) {
        int e = i & 7, lane = (i >> 3) & 63, q = i >> 9;   // q = kx*3+ch
        int kx = q / 3, ch = q % 3;
        int oc = lane & 15, dy = (lane >> 4) & 1, rr = lane >> 5;
        int ky = ch * 2 + rr - dy;
        float w = 0.f;
        if (e < 6 && ky >= 0 && ky <= 4) w = Wfull[(oc * 6 + e) * 25 + ky * 5 + kx];
        _Float16 hw = (_Float16)w;
        AF[i] = __builtin_bit_cast(unsigned short, hw);
    }
    if (tid < 6)        bias[tid] = b3[tid];
    else if (tid < 15)  bias[tid] = b4[tid - 6];
    else if (tid == 15) bias[tid] = b6[0];
}

__device__ __forceinline__ void pack2(const float2 (&v)[6], uint4& wA, uint4& wB) {
    h2 a0; a0.x = (_Float16)v[0].x; a0.y = (_Float16)v[1].x;
    h2 a1; a1.x = (_Float16)v[2].x; a1.y = (_Float16)v[3].x;
    h2 a2; a2.x = (_Float16)v[4].x; a2.y = (_Float16)v[5].x;
    h2 b0; b0.x = (_Float16)v[0].y; b0.y = (_Float16)v[1].y;
    h2 b1; b1.x = (_Float16)v[2].y; b1.y = (_Float16)v[3].y;
    h2 b2; b2.x = (_Float16)v[4].y; b2.y = (_Float16)v[5].y;
    wA.x = __builtin_bit_cast(unsigned int, a0);
    wA.y = __builtin_bit_cast(unsigned int, a1);
    wA.z = __builtin_bit_cast(unsigned int, a2);
    wA.w = 0u;
    wB.x = __builtin_bit_cast(unsigned int, b0);
    wB.y = __builtin_bit_cast(unsigned int, b1);
    wB.z = __builtin_bit_cast(unsigned int, b2);
    wB.w = 0u;
}

__global__ __launch_bounds__(512, 4) void conv_mfma(
        const float* __restrict__ x, const unsigned short* __restrict__ AF,
        const float* __restrict__ bias, float* __restrict__ out) {
    __shared__ uint4 T4[32 * TC];   // 34816 B, slot-major: block = slot*TC + col

    const int tid = threadIdx.x;

    // XCD-coherent remap (bijective on 4096): xcd = id&7 (round-robin dispatch)
    const int id  = blockIdx.x + 8 * (blockIdx.y + 16 * blockIdx.z);
    const int xcd = id & 7;
    const int pos = id >> 3;                 // 0..511
    const int bz  = xcd * 4 + (pos >> 7);
    const int by  = (pos >> 3) & 15;
    const int bx  = pos & 7;

    const int gx0 = bx * BX;
    const int Y0  = by * 32;                 // output rows Y0 .. Y0+31
    const float* xb = x + (size_t)bz * 6 * 512 * 512;

    const int lane = tid & 63;
    const int h = lane >> 5;                 // K-half (verified R6 mapping)

    h8 afr[15];
    #pragma unroll
    for (int q = 0; q < 15; ++q)
        afr[q] = *reinterpret_cast<const h8*>(AF + (q * 64 + lane) * 8);

    float bv[8];
    #pragma unroll
    for (int r8 = 0; r8 < 8; ++r8)
        bv[r8] = bias[(r8 & 3) + 8 * (r8 >> 2) + 4 * h];

    // ---- prologue: stage input rows Y0..Y0+19 into slots 0..19 (Y0%32==0)
    #pragma unroll
    for (int k = 0; k < 2; ++k) {
        int idx = tid + k * 512;
        if (idx < 680) {
            int cp = idx % 34, rr = idx / 34;
            int c = 2 * cp, gx = gx0 + c, gy = Y0 + rr;   // gy <= 499 < 512
            float2 v[6];
            #pragma unroll
            for (int ic = 0; ic < 6; ++ic) v[ic] = (float2){0.f, 0.f};
            if (gx < 512) {
                const float* rp = xb + (size_t)gy * 512 + gx;
                #pragma unroll
                for (int ic = 0; ic < 6; ++ic)
                    v[ic] = *(const float2*)(rp + (size_t)ic * 262144);
            }
            uint4 wA, wB;
            pack2(v, wA, wB);
            T4[rr * TC + c]     = wA;
            T4[rr * TC + c + 1] = wB;
        }
    }
    __syncthreads();

    const int wv = tid >> 6;
    const int s  = wv & 1;                   // px strip
    const int dh = (wv >> 1) & 1;            // d half (rows 4*dh..4*dh+3 of phase)
    const int ch = wv >> 2;                  // chain (rows +2*ch)
    const int colb = s * 32 + (lane & 31);
    const int px = gx0 + colb;
    const bool pxok = (px < OW);
    const size_t cs = (size_t)OW * OW;
    float* ob = out + ((size_t)bz * 16 + 4 * h) * cs + px;

    #pragma unroll 1
    for (int t = 0; t < 4; ++t) {
        // -- issue loads for input rows Y0+8t+20 .. +27 (consumed at phase t+2)
        float2 va[6];
        int wslot = -1, wcol = 0;
        if (tid < 272) {
            int cp = tid % 34, rr = tid / 34;
            int c = 2 * cp, gx = gx0 + c, gy = Y0 + 8 * t + 20 + rr;
            #pragma unroll
            for (int ic = 0; ic < 6; ++ic) va[ic] = (float2){0.f, 0.f};
            if (gy < 512 && gx < 512) {
                const float* rp = xb + (size_t)gy * 512 + gx;
                #pragma unroll
                for (int ic = 0; ic < 6; ++ic)
                    va[ic] = *(const float2*)(rp + (size_t)ic * 262144);
            }
            wslot = gy & RM;
            wcol = c;
        }

        // -- compute: one chain (15 ds_read_b128 + 15 MFMA)
        const int sb = 8 * t + 4 * dh + 2 * ch + h;      // window-row offset
        const int s0 = sb & RM, s1 = (sb + 2) & RM, s2 = (sb + 4) & RM;
        f32x16 acc;
        #pragma unroll
        for (int r = 0; r < 16; ++r) acc[r] = 0.f;
        #pragma unroll
        for (int kx = 0; kx < 5; ++kx) {
            h8 b0 = *reinterpret_cast<const h8*>(&T4[s0 * TC + colb + kx]);
            h8 b1 = *reinterpret_cast<const h8*>(&T4[s1 * TC + colb + kx]);
            h8 b2 = *reinterpret_cast<const h8*>(&T4[s2 * TC + colb + kx]);
            acc = __builtin_amdgcn_mfma_f32_32x32x16_f16(afr[kx * 3 + 0], b0, acc, 0, 0, 0);
            acc = __builtin_amdgcn_mfma_f32_32x32x16_f16(afr[kx * 3 + 1], b1, acc, 0, 0, 0);
            acc = __builtin_amdgcn_mfma_f32_32x32x16_f16(afr[kx * 3 + 2], b2, acc, 0, 0, 0);
        }

        // -- stores (bias folded here; binit regs traded for bv[8])
        const int oyb = Y0 + 8 * t + 4 * dh + 2 * ch;
        #pragma unroll
        for (int dy = 0; dy < 2; ++dy) {
            const int oy = oyb + dy;
            if (oy < OW && pxok) {
                #pragma unroll
                for (int r8 = 0; r8 < 8; ++r8) {
                    const int ocb = (r8 & 3) + 8 * (r8 >> 2);
                    ob[(size_t)ocb * cs + (size_t)oy * OW] = acc[dy * 8 + r8] + bv[r8];
                }
            }
        }

        // -- commit staged rows (slots 8t+20..27 mod 32: disjoint from all
        //    reads until phase t+2; one barrier per phase suffices)
        if (wslot >= 0) {
            uint4 wA, wB;
            pack2(va, wA, wB);
            T4[wslot * TC + wcol]     = wA;
            T4[wslot * TC + wcol + 1] = wB;
        }
        __syncthreads();
    }
}

extern "C" void kernel_launch(void* const* d_in, const int* in_sizes, int n_in,
                              void* d_out, int out_size, void* d_ws, size_t ws_size,
                              hipStream_t stream) {
    const float* x  = (const float*)d_in[0];
    const float* w3 = (const float*)d_in[1];
    const float* b3 = (const float*)d_in[2];
    const float* w4 = (const float*)d_in[3];
    const float* b4 = (const float*)d_in[4];
    const float* w6 = (const float*)d_in[5];
    const float* b6 = (const float*)d_in[6];
    float* out = (float*)d_out;

    float* bias        = (float*)d_ws;                    // 16 f32
    unsigned short* AF = (unsigned short*)(bias + 16);    // 7680 u16

    prep_weights<<<1, 256, 0, stream>>>(w3, b3, w4, b4, w6, b6, bias, AF);

    dim3 grid(8, 16, 32);   // remapped in-kernel to XCD-coherent slabs
    conv_mfma<<<grid, 512, 0, stream>>>(x, AF, bias, out);
}

// Round 16
// 225.661 us; speedup vs baseline: 1.1458x; 1.0061x over previous
//
#include <hip/hip_runtime.h>

// C3-style layer via MFMA implicit GEMM, R15 = R14 ring-walk with:
//  (a) prefetch only at t<2 (R14 fetched 16 useless rows/block = 44% input
//      over-fetch),
//  (b) raw lgkmcnt(0)+s_barrier ring barriers (no vmcnt(0) store drain as in
//      __syncthreads -> output stores stay in flight across phases),
//  (c) barriers only after prologue/t0/t1 (t2,t3 reads ordered by t1 barrier).
// Keeps R13's XCD-coherent batch-slab remap.  MFMA/A-frag/C mappings
// verbatim from verified R6..R14.
// x[32,6,512,512] f32 -> out[32,16,508,508] f32 (5x5 VALID conv; sparse
// oc<-ic connectivity via zero weights in dense [16,6,5,5] kernel).

#define OW 508
#define BX 64     // output px per block; 2 strips x 32
#define TC 68     // staged columns = BX + 4
#define RM 31     // ring mask (32 slots)

typedef _Float16 h8 __attribute__((ext_vector_type(8)));
typedef _Float16 h2 __attribute__((ext_vector_type(2)));
typedef float f32x16 __attribute__((ext_vector_type(16)));

__device__ __constant__ int d_CH3[6][3] = {
    {0,1,2},{1,2,3},{2,3,4},{3,4,5},{0,4,5},{0,1,5}};
__device__ __constant__ int d_CH4[9][4] = {
    {0,1,2,3},{1,2,3,4},{2,3,4,5},{0,3,4,5},{0,1,4,5},
    {0,1,2,5},{0,1,3,4},{1,2,4,5},{0,2,3,5}};

// ws: bias f32[16] | AF ushort[15*64*8]
// AF[((kx*3+ch)*64 + lane)*8 + e]: A-frag: oc=lane&15, dy=(lane>>4)&1,
// rr=lane>>5, ky=ch*2+rr-dy; value W[oc][e][ky][kx] or 0.  (verified R6)
__global__ void prep_weights(const float* __restrict__ w3, const float* __restrict__ b3,
                             const float* __restrict__ w4, const float* __restrict__ b4,
                             const float* __restrict__ w6, const float* __restrict__ b6,
                             float* __restrict__ bias, unsigned short* __restrict__ AF) {
    __shared__ float Wfull[16 * 6 * 25];   // dense [oc][ic][tap]
    const int tid = threadIdx.x;
    for (int i = tid; i < 16 * 6 * 25; i += 256) Wfull[i] = 0.f;
    __syncthreads();
    for (int i = tid; i < 6 * 3 * 25; i += 256) {
        int oc = i / 75, r = i % 75, c = r / 25, t = r % 25;
        Wfull[(oc * 6 + d_CH3[oc][c]) * 25 + t] = w3[i];
    }
    for (int i = tid; i < 9 * 4 * 25; i += 256) {
        int o = i / 100, r = i % 100, c = r / 25, t = r % 25;
        Wfull[((6 + o) * 6 + d_CH4[o][c]) * 25 + t] = w4[i];
    }
    for (int i = tid; i < 6 * 25; i += 256) Wfull[15 * 150 + i] = w6[i];
    __syncthreads();
    for (int i = tid; i < 15 * 64 * 8; i += 256) {
        int e = i & 7, lane = (i >> 3) & 63, q = i >> 9;   // q = kx*3+ch
        int kx = q / 3, ch = q % 3;
        int oc = lane & 15, dy = (lane >> 4) & 1, rr = lane >> 5;
        int ky = ch * 2 + rr - dy;
        float w = 0.f;
        if (e < 6 && ky >= 0 && ky <= 4) w = Wfull[(oc * 6 + e) * 25 + ky * 5 + kx];
        _Float16 hw = (_Float16)w;
        AF[i] = __builtin_bit_cast(unsigned short, hw);
    }
    if (tid < 6)        bias[tid] = b3[tid];
    else if (tid < 15)  bias[tid] = b4[tid - 6];
    else if (tid == 15) bias[tid] = b6[0];
}

__device__ __forceinline__ void pack2(const float2 (&v)[6], uint4& wA, uint4& wB) {
    h2 a0; a0.x = (_Float16)v[0].x; a0.y = (_Float16)v[1].x;
    h2 a1; a1.x = (_Float16)v[2].x; a1.y = (_Float16)v[3].x;
    h2 a2; a2.x = (_Float16)v[4].x; a2.y = (_Float16)v[5].x;
    h2 b0; b0.x = (_Float16)v[0].y; b0.y = (_Float16)v[1].y;
    h2 b1; b1.x = (_Float16)v[2].y; b1.y = (_Float16)v[3].y;
    h2 b2; b2.x = (_Float16)v[4].y; b2.y = (_Float16)v[5].y;
    wA.x = __builtin_bit_cast(unsigned int, a0);
    wA.y = __builtin_bit_cast(unsigned int, a1);
    wA.z = __builtin_bit_cast(unsigned int, a2);
    wA.w = 0u;
    wB.x = __builtin_bit_cast(unsigned int, b0);
    wB.y = __builtin_bit_cast(unsigned int, b1);
    wB.z = __builtin_bit_cast(unsigned int, b2);
    wB.w = 0u;
}

// Ring barrier: order ds_writes (lgkmcnt) across waves WITHOUT draining
// in-flight global stores (vmcnt) like __syncthreads does.
__device__ __forceinline__ void ring_barrier() {
    asm volatile("s_waitcnt lgkmcnt(0)" ::: "memory");
    __builtin_amdgcn_s_barrier();
    __builtin_amdgcn_sched_barrier(0);   // rule #18: nothing crosses
}

__global__ __launch_bounds__(512, 4) void conv_mfma(
        const float* __restrict__ x, const unsigned short* __restrict__ AF,
        const float* __restrict__ bias, float* __restrict__ out) {
    __shared__ uint4 T4[32 * TC];   // 34816 B, slot-major: block = slot*TC + col

    const int tid = threadIdx.x;

    // XCD-coherent remap (bijective on 4096): xcd = id&7 (round-robin dispatch)
    const int id  = blockIdx.x + 8 * (blockIdx.y + 16 * blockIdx.z);
    const int xcd = id & 7;
    const int pos = id >> 3;                 // 0..511
    const int bz  = xcd * 4 + (pos >> 7);
    const int by  = (pos >> 3) & 15;
    const int bx  = pos & 7;

    const int gx0 = bx * BX;
    const int Y0  = by * 32;                 // output rows Y0 .. Y0+31
    const float* xb = x + (size_t)bz * 6 * 512 * 512;

    const int lane = tid & 63;
    const int h = lane >> 5;                 // K-half (verified R6 mapping)

    h8 afr[15];
    #pragma unroll
    for (int q = 0; q < 15; ++q)
        afr[q] = *reinterpret_cast<const h8*>(AF + (q * 64 + lane) * 8);

    float bv[8];
    #pragma unroll
    for (int r8 = 0; r8 < 8; ++r8)
        bv[r8] = bias[(r8 & 3) + 8 * (r8 >> 2) + 4 * h];

    // ---- prologue: stage input rows Y0..Y0+19 into slots 0..19 (Y0%32==0)
    #pragma unroll
    for (int k = 0; k < 2; ++k) {
        int idx = tid + k * 512;
        if (idx < 680) {
            int cp = idx % 34, rr = idx / 34;
            int c = 2 * cp, gx = gx0 + c, gy = Y0 + rr;   // gy <= 499 < 512
            float2 v[6];
            #pragma unroll
            for (int ic = 0; ic < 6; ++ic) v[ic] = (float2){0.f, 0.f};
            if (gx < 512) {
                const float* rp = xb + (size_t)gy * 512 + gx;
                #pragma unroll
                for (int ic = 0; ic < 6; ++ic)
                    v[ic] = *(const float2*)(rp + (size_t)ic * 262144);
            }
            uint4 wA, wB;
            pack2(v, wA, wB);
            T4[rr * TC + c]     = wA;
            T4[rr * TC + c + 1] = wB;
        }
    }
    ring_barrier();

    const int wv = tid >> 6;
    const int s  = wv & 1;                   // px strip
    const int dh = (wv >> 1) & 1;            // d half (rows 4*dh..4*dh+3 of phase)
    const int ch = wv >> 2;                  // chain (rows +2*ch)
    const int colb = s * 32 + (lane & 31);
    const int px = gx0 + colb;
    const bool pxok = (px < OW);
    const size_t cs = (size_t)OW * OW;
    float* ob = out + ((size_t)bz * 16 + 4 * h) * cs + px;

    #pragma unroll 1
    for (int t = 0; t < 4; ++t) {
        // -- issue loads for input rows Y0+8t+20..+27 (consumed at phase t+2).
        //    Only t<2 produces rows that are ever consumed (fix of R14's 44%
        //    input over-fetch).
        float2 va[6];
        int wslot = -1, wcol = 0;
        if (t < 2 && tid < 272) {
            int cp = tid % 34, rr = tid / 34;
            int c = 2 * cp, gx = gx0 + c, gy = Y0 + 8 * t + 20 + rr;
            #pragma unroll
            for (int ic = 0; ic < 6; ++ic) va[ic] = (float2){0.f, 0.f};
            if (gy < 512 && gx < 512) {
                const float* rp = xb + (size_t)gy * 512 + gx;
                #pragma unroll
                for (int ic = 0; ic < 6; ++ic)
                    va[ic] = *(const float2*)(rp + (size_t)ic * 262144);
            }
            wslot = gy & RM;   // wrap rows >=512 commit zeros into slots that
            wcol = c;          // only feed oy>=OW-masked outputs (derived safe)
        }

        // -- compute: one chain (15 ds_read_b128 + 15 MFMA)
        const int sb = 8 * t + 4 * dh + 2 * ch + h;      // window-row offset
        const int s0 = sb & RM, s1 = (sb + 2) & RM, s2 = (sb + 4) & RM;
        f32x16 acc;
        #pragma unroll
        for (int r = 0; r < 16; ++r) acc[r] = 0.f;
        #pragma unroll
        for (int kx = 0; kx < 5; ++kx) {
            h8 b0 = *reinterpret_cast<const h8*>(&T4[s0 * TC + colb + kx]);
            h8 b1 = *reinterpret_cast<const h8*>(&T4[s1 * TC + colb + kx]);
            h8 b2 = *reinterpret_cast<const h8*>(&T4[s2 * TC + colb + kx]);
            acc = __builtin_amdgcn_mfma_f32_32x32x16_f16(afr[kx * 3 + 0], b0, acc, 0, 0, 0);
            acc = __builtin_amdgcn_mfma_f32_32x32x16_f16(afr[kx * 3 + 1], b1, acc, 0, 0, 0);
            acc = __builtin_amdgcn_mfma_f32_32x32x16_f16(afr[kx * 3 + 2], b2, acc, 0, 0, 0);
        }

        // -- stores (bias folded; stores stay in flight across ring_barrier)
        const int oyb = Y0 + 8 * t + 4 * dh + 2 * ch;
        #pragma unroll
        for (int dy = 0; dy < 2; ++dy) {
            const int oy = oyb + dy;
            if (oy < OW && pxok) {
                #pragma unroll
                for (int r8 = 0; r8 < 8; ++r8) {
                    const int ocb = (r8 & 3) + 8 * (r8 >> 2);
                    ob[(size_t)ocb * cs + (size_t)oy * OW] = acc[dy * 8 + r8] + bv[r8];
                }
            }
        }

        // -- commit staged rows + ring barrier (only needed for t<2: t2/t3
        //    reads are ordered by the t1 barrier; commit slots disjoint from
        //    concurrent reads by construction)
        if (t < 2) {
            if (wslot >= 0) {
                uint4 wA, wB;
                pack2(va, wA, wB);
                T4[wslot * TC + wcol]     = wA;
                T4[wslot * TC + wcol + 1] = wB;
            }
            ring_barrier();
        }
    }
}

extern "C" void kernel_launch(void* const* d_in, const int* in_sizes, int n_in,
                              void* d_out, int out_size, void* d_ws, size_t ws_size,
                              hipStream_t stream) {
    const float* x  = (const float*)d_in[0];
    const float* w3 = (const float*)d_in[1];
    const float* b3 = (const float*)d_in[2];
    const float* w4 = (const float*)d_in[3];
    const float* b4 = (const float*)d_in[4];
    const float* w6 = (const float*)d_in[5];
    const float* b6 = (const float*)d_in[6];
    float* out = (float*)d_out;

    float* bias        = (float*)d_ws;                    // 16 f32
    unsigned short* AF = (unsigned short*)(bias + 16);    // 7680 u16

    prep_weights<<<1, 256, 0, stream>>>(w3, b3, w4, b4, w6, b6, bias, AF);

    dim3 grid(8, 16, 32);   // remapped in-kernel to XCD-coherent slabs
    conv_mfma<<<grid, 512, 0, stream>>>(x, AF, bias, out);
}

// Round 17
// 221.185 us; speedup vs baseline: 1.1689x; 1.0202x over previous
//
#include <hip/hip_runtime.h>

// C3-style layer via MFMA implicit GEMM, R16 = R15 with a 64-row y-walk
// (8 phases/block, prefetch t<6): halves the number of prologue bursts
// (R15: 20 of 36 fetched rows = 55% in a latency-exposed serial prologue,
// 4-phase block life) and halves y-halo overlap.  Ring disjointness
// re-derived for 8 phases.  Keeps slot-major LDS, XCD slab remap,
// lgkm-only ring barriers.  MFMA/A-frag/C mappings verbatim R6..R15.
// x[32,6,512,512] f32 -> out[32,16,508,508] f32 (5x5 VALID conv; sparse
// oc<-ic connectivity via zero weights in dense [16,6,5,5] kernel).

#define OW 508
#define BX 64     // output px per block; 2 strips x 32
#define TC 68     // staged columns = BX + 4
#define RM 31     // ring mask (32 slots)

typedef _Float16 h8 __attribute__((ext_vector_type(8)));
typedef _Float16 h2 __attribute__((ext_vector_type(2)));
typedef float f32x16 __attribute__((ext_vector_type(16)));

__device__ __constant__ int d_CH3[6][3] = {
    {0,1,2},{1,2,3},{2,3,4},{3,4,5},{0,4,5},{0,1,5}};
__device__ __constant__ int d_CH4[9][4] = {
    {0,1,2,3},{1,2,3,4},{2,3,4,5},{0,3,4,5},{0,1,4,5},
    {0,1,2,5},{0,1,3,4},{1,2,4,5},{0,2,3,5}};

// ws: bias f32[16] | AF ushort[15*64*8]
// AF[((kx*3+ch)*64 + lane)*8 + e]: A-frag: oc=lane&15, dy=(lane>>4)&1,
// rr=lane>>5, ky=ch*2+rr-dy; value W[oc][e][ky][kx] or 0.  (verified R6)
__global__ void prep_weights(const float* __restrict__ w3, const float* __restrict__ b3,
                             const float* __restrict__ w4, const float* __restrict__ b4,
                             const float* __restrict__ w6, const float* __restrict__ b6,
                             float* __restrict__ bias, unsigned short* __restrict__ AF) {
    __shared__ float Wfull[16 * 6 * 25];   // dense [oc][ic][tap]
    const int tid = threadIdx.x;
    for (int i = tid; i < 16 * 6 * 25; i += 256) Wfull[i] = 0.f;
    __syncthreads();
    for (int i = tid; i < 6 * 3 * 25; i += 256) {
        int oc = i / 75, r = i % 75, c = r / 25, t = r % 25;
        Wfull[(oc * 6 + d_CH3[oc][c]) * 25 + t] = w3[i];
    }
    for (int i = tid; i < 9 * 4 * 25; i += 256) {
        int o = i / 100, r = i % 100, c = r / 25, t = r % 25;
        Wfull[((6 + o) * 6 + d_CH4[o][c]) * 25 + t] = w4[i];
    }
    for (int i = tid; i < 6 * 25; i += 256) Wfull[15 * 150 + i] = w6[i];
    __syncthreads();
    for (int i = tid; i < 15 * 64 * 8; i += 256) {
        int e = i & 7, lane = (i >> 3) & 63, q = i >> 9;   // q = kx*3+ch
        int kx = q / 3, ch = q % 3;
        int oc = lane & 15, dy = (lane >> 4) & 1, rr = lane >> 5;
        int ky = ch * 2 + rr - dy;
        float w = 0.f;
        if (e < 6 && ky >= 0 && ky <= 4) w = Wfull[(oc * 6 + e) * 25 + ky * 5 + kx];
        _Float16 hw = (_Float16)w;
        AF[i] = __builtin_bit_cast(unsigned short, hw);
    }
    if (tid < 6)        bias[tid] = b3[tid];
    else if (tid < 15)  bias[tid] = b4[tid - 6];
    else if (tid == 15) bias[tid] = b6[0];
}

__device__ __forceinline__ void pack2(const float2 (&v)[6], uint4& wA, uint4& wB) {
    h2 a0; a0.x = (_Float16)v[0].x; a0.y = (_Float16)v[1].x;
    h2 a1; a1.x = (_Float16)v[2].x; a1.y = (_Float16)v[3].x;
    h2 a2; a2.x = (_Float16)v[4].x; a2.y = (_Float16)v[5].x;
    h2 b0; b0.x = (_Float16)v[0].y; b0.y = (_Float16)v[1].y;
    h2 b1; b1.x = (_Float16)v[2].y; b1.y = (_Float16)v[3].y;
    h2 b2; b2.x = (_Float16)v[4].y; b2.y = (_Float16)v[5].y;
    wA.x = __builtin_bit_cast(unsigned int, a0);
    wA.y = __builtin_bit_cast(unsigned int, a1);
    wA.z = __builtin_bit_cast(unsigned int, a2);
    wA.w = 0u;
    wB.x = __builtin_bit_cast(unsigned int, b0);
    wB.y = __builtin_bit_cast(unsigned int, b1);
    wB.z = __builtin_bit_cast(unsigned int, b2);
    wB.w = 0u;
}

// Ring barrier: order ds_writes (lgkmcnt) across waves WITHOUT draining
// in-flight global stores (vmcnt) like __syncthreads does.
__device__ __forceinline__ void ring_barrier() {
    asm volatile("s_waitcnt lgkmcnt(0)" ::: "memory");
    __builtin_amdgcn_s_barrier();
    __builtin_amdgcn_sched_barrier(0);   // rule #18: nothing crosses
}

__global__ __launch_bounds__(512, 4) void conv_mfma(
        const float* __restrict__ x, const unsigned short* __restrict__ AF,
        const float* __restrict__ bias, float* __restrict__ out) {
    __shared__ uint4 T4[32 * TC];   // 34816 B, slot-major: block = slot*TC + col

    const int tid = threadIdx.x;

    // XCD-coherent remap (bijective on 2048): xcd = id&7 (round-robin dispatch)
    const int id  = blockIdx.x + 8 * (blockIdx.y + 8 * blockIdx.z);
    const int xcd = id & 7;
    const int pos = id >> 3;                 // 0..255
    const int bz  = xcd * 4 + (pos >> 6);
    const int by  = (pos >> 3) & 7;
    const int bx  = pos & 7;

    const int gx0 = bx * BX;
    const int Y0  = by * 64;                 // output rows Y0 .. Y0+63
    const float* xb = x + (size_t)bz * 6 * 512 * 512;

    const int lane = tid & 63;
    const int h = lane >> 5;                 // K-half (verified R6 mapping)

    h8 afr[15];
    #pragma unroll
    for (int q = 0; q < 15; ++q)
        afr[q] = *reinterpret_cast<const h8*>(AF + (q * 64 + lane) * 8);

    float bv[8];
    #pragma unroll
    for (int r8 = 0; r8 < 8; ++r8)
        bv[r8] = bias[(r8 & 3) + 8 * (r8 >> 2) + 4 * h];

    // ---- prologue: stage input rows Y0..Y0+19 into slots 0..19 (Y0%32==0;
    //      Y0<=448 so gy<=467<512 always)
    #pragma unroll
    for (int k = 0; k < 2; ++k) {
        int idx = tid + k * 512;
        if (idx < 680) {
            int cp = idx % 34, rr = idx / 34;
            int c = 2 * cp, gx = gx0 + c, gy = Y0 + rr;
            float2 v[6];
            #pragma unroll
            for (int ic = 0; ic < 6; ++ic) v[ic] = (float2){0.f, 0.f};
            if (gx < 512) {
                const float* rp = xb + (size_t)gy * 512 + gx;
                #pragma unroll
                for (int ic = 0; ic < 6; ++ic)
                    v[ic] = *(const float2*)(rp + (size_t)ic * 262144);
            }
            uint4 wA, wB;
            pack2(v, wA, wB);
            T4[rr * TC + c]     = wA;
            T4[rr * TC + c + 1] = wB;
        }
    }
    ring_barrier();

    const int wv = tid >> 6;
    const int s  = wv & 1;                   // px strip
    const int dh = (wv >> 1) & 1;            // d half (rows 4*dh..4*dh+3 of phase)
    const int ch = wv >> 2;                  // chain (rows +2*ch)
    const int colb = s * 32 + (lane & 31);
    const int px = gx0 + colb;
    const bool pxok = (px < OW);
    const size_t cs = (size_t)OW * OW;
    float* ob = out + ((size_t)bz * 16 + 4 * h) * cs + px;

    #pragma unroll 1
    for (int t = 0; t < 8; ++t) {
        // -- issue loads for input rows Y0+8t+20..+27 (consumed at phase t+2;
        //    rows exist only for t<6)
        float2 va[6];
        int wslot = -1, wcol = 0;
        if (t < 6 && tid < 272) {
            int cp = tid % 34, rr = tid / 34;
            int c = 2 * cp, gx = gx0 + c, gy = Y0 + 8 * t + 20 + rr;
            #pragma unroll
            for (int ic = 0; ic < 6; ++ic) va[ic] = (float2){0.f, 0.f};
            if (gy < 512 && gx < 512) {
                const float* rp = xb + (size_t)gy * 512 + gx;
                #pragma unroll
                for (int ic = 0; ic < 6; ++ic)
                    va[ic] = *(const float2*)(rp + (size_t)ic * 262144);
            }
            wslot = gy & RM;   // wrap rows >=512 commit zeros; they feed only
            wcol = c;          // oy>=OW-masked outputs (derived safe)
        }

        // -- compute: one chain (15 ds_read_b128 + 15 MFMA)
        const int sb = 8 * t + 4 * dh + 2 * ch + h;      // window-row offset
        const int s0 = sb & RM, s1 = (sb + 2) & RM, s2 = (sb + 4) & RM;
        f32x16 acc;
        #pragma unroll
        for (int r = 0; r < 16; ++r) acc[r] = 0.f;
        #pragma unroll
        for (int kx = 0; kx < 5; ++kx) {
            h8 b0 = *reinterpret_cast<const h8*>(&T4[s0 * TC + colb + kx]);
            h8 b1 = *reinterpret_cast<const h8*>(&T4[s1 * TC + colb + kx]);
            h8 b2 = *reinterpret_cast<const h8*>(&T4[s2 * TC + colb + kx]);
            acc = __builtin_amdgcn_mfma_f32_32x32x16_f16(afr[kx * 3 + 0], b0, acc, 0, 0, 0);
            acc = __builtin_amdgcn_mfma_f32_32x32x16_f16(afr[kx * 3 + 1], b1, acc, 0, 0, 0);
            acc = __builtin_amdgcn_mfma_f32_32x32x16_f16(afr[kx * 3 + 2], b2, acc, 0, 0, 0);
        }

        // -- stores (bias folded; stores stay in flight across ring_barrier)
        const int oyb = Y0 + 8 * t + 4 * dh + 2 * ch;
        #pragma unroll
        for (int dy = 0; dy < 2; ++dy) {
            const int oy = oyb + dy;
            if (oy < OW && pxok) {
                #pragma unroll
                for (int r8 = 0; r8 < 8; ++r8) {
                    const int ocb = (r8 & 3) + 8 * (r8 >> 2);
                    ob[(size_t)ocb * cs + (size_t)oy * OW] = acc[dy * 8 + r8] + bv[r8];
                }
            }
        }

        // -- commit staged rows + ring barrier (t<6; commit slots disjoint
        //    from all reads until phase t+2 -- re-derived for 8 phases)
        if (t < 6) {
            if (wslot >= 0) {
                uint4 wA, wB;
                pack2(va, wA, wB);
                T4[wslot * TC + wcol]     = wA;
                T4[wslot * TC + wcol + 1] = wB;
            }
            ring_barrier();
        }
    }
}

extern "C" void kernel_launch(void* const* d_in, const int* in_sizes, int n_in,
                              void* d_out, int out_size, void* d_ws, size_t ws_size,
                              hipStream_t stream) {
    const float* x  = (const float*)d_in[0];
    const float* w3 = (const float*)d_in[1];
    const float* b3 = (const float*)d_in[2];
    const float* w4 = (const float*)d_in[3];
    const float* b4 = (const float*)d_in[4];
    const float* w6 = (const float*)d_in[5];
    const float* b6 = (const float*)d_in[6];
    float* out = (float*)d_out;

    float* bias        = (float*)d_ws;                    // 16 f32
    unsigned short* AF = (unsigned short*)(bias + 16);    // 7680 u16

    prep_weights<<<1, 256, 0, stream>>>(w3, b3, w4, b4, w6, b6, bias, AF);

    dim3 grid(8, 8, 32);   // remapped in-kernel to XCD-coherent slabs
    conv_mfma<<<grid, 512, 0, stream>>>(x, AF, bias, out);
}